// Round 4
// baseline (238.742 us; speedup 1.0000x reference)
//
#include <hip/hip_runtime.h>

#define C_CH 16
#define Hdim 128
#define Wdim 128
#define HWdim 16384
#define CHW (C_CH * HWdim)                 // 262144 floats: one [C][H][W] slab
#define Bdim 2
#define PAIR_ELEMS (Bdim * CHW)            // 524288

// x canvas: border 6 (= 2*max PAD, fused kernel needs double halo)
#define XWP 140
#define XHP 140
#define XPL (XHP * XWP)                    // 19600 per pair-plane

// tg att canvas: border 3 (single halo)
#define HP 134
#define WP 136
#define PL (HP * WP)                       // 18224

typedef float v2f __attribute__((ext_vector_type(2)));
typedef _Float16 h2 __attribute__((ext_vector_type(2)));
typedef _Float16 f16x8 __attribute__((ext_vector_type(8)));
typedef float f32x4 __attribute__((ext_vector_type(4)));

__device__ __forceinline__ v2f unpack2(unsigned u) {
  h2 h = __builtin_bit_cast(h2, u);
  return (v2f){(float)h.x, (float)h.y};
}
__device__ __forceinline__ unsigned pack2(float a, float b) {
  h2 h = {(_Float16)a, (_Float16)b};
  return __builtin_bit_cast(unsigned, h);
}

template<int P> struct SimSR { static constexpr int v = (P == 7) ? 20 : 12; };

// ---------------------------------------------------------------------------
// Prep.
//  memT[d][m]  f32 (tg sim VALU)
//  memR[m][u][v][c] f32 flipped (tg read VALU)
//  simA: bg sim MFMA A, scaled, hi/lo, K=32 packs 2uv x 16c:
//    half idx = (uvp*8 + s*4 + mt)*512 + row*32 + (kg^(row&3))*8 + kl
//      uvp=uv>>1 (unflipped), kk=(uv&1)*16+c, kg=kk>>3, kl=kk&7, mt=m>>4,row=m&15
//  readA: bg read MFMA A, unscaled, flipped, hi/lo, K=32 = 32 m of one uv:
//    half idx = uvf*2048 + (ck*2+s)*512 + c*32 + (kg^(c&3))*8 + kl
//      uvf=flip(uv), ck=m>>5, kg=(m&31)>>3, kl=m&7
// ---------------------------------------------------------------------------
struct PrepDesc {
  const float* mem;
  const float* temp;
  float* memT;
  float* memR;          // tg only (else null)
  _Float16* simA;       // bg only (else null)
  _Float16* readA;      // bg only (else null)
  int M, D, P;
};
struct PrepArgs { PrepDesc d[6]; };

__global__ __launch_bounds__(256) void k_prep(PrepArgs a) {
  PrepDesc de = a.d[blockIdx.y];
  int n = de.M * de.D;
  int idx = blockIdx.x * 256 + threadIdx.x;
  if (idx >= n) return;
  int m = idx / de.D;
  int d = idx - m * de.D;
  float val = de.mem[idx];
  float sc = de.temp[0] / sqrtf((float)de.D);
  de.memT[d * de.M + m] = val * sc;
  int pp = de.P * de.P;
  int c = d / pp;
  int r = d - c * pp;
  int i = r / de.P;
  int j = r - i * de.P;
  if (de.memR)
    de.memR[((m * de.P + (de.P - 1 - i)) * de.P + (de.P - 1 - j)) * C_CH + c] = val;
  if (de.simA) {
    int uv = i * de.P + j;                 // unflipped (correlation)
    int uvp = uv >> 1, luv = uv & 1;
    int kk = luv * 16 + c, kg = kk >> 3, kl = kk & 7;
    int mt = m >> 4, row = m & 15;
    float sv = val * sc;
    _Float16 hi = (_Float16)sv;
    size_t bi = ((size_t)uvp * 8 + mt) * 512 + row * 32 + (size_t)((kg ^ (row & 3)) * 8 + kl);
    de.simA[bi] = hi;                      // s=0
    de.simA[bi + 2048] = (_Float16)(sv - (float)hi);   // s=1 (+4*512)
  }
  if (de.readA) {
    int u = de.P - 1 - i, v = de.P - 1 - j;
    int uvf = u * de.P + v;
    int ck = m >> 5, m5 = m & 31, kg = m5 >> 3, kl = m5 & 7;
    _Float16 hi = (_Float16)val;
    size_t bi = (size_t)uvf * 2048 + (size_t)(ck * 2) * 512 + c * 32 +
                (size_t)((kg ^ (c & 3)) * 8 + kl);
    de.readA[bi] = hi;
    de.readA[bi + 512] = (_Float16)(val - (float)hi);
  }
}

// ---------------------------------------------------------------------------
// Build f16 c-pair-packed padded canvas (border 6).
// ---------------------------------------------------------------------------
__global__ __launch_bounds__(256) void k_padx(const float* __restrict__ bg,
                                              const float* __restrict__ tg,
                                              unsigned* __restrict__ xpad2)
{
  int idx = blockIdx.x * 256 + threadIdx.x;     // 32 pair-planes * HW
  int pp = idx >> 14;
  int hw = idx & (HWdim - 1);
  int y = hw >> 7, x = hw & 127;
  int z = pp >> 3, cp = pp & 7;
  const float* src = (z < 2) ? bg : tg;
  int b = z & 1;
  float a = src[((b * C_CH + 2 * cp) << 14) + hw];
  float bb = src[((b * C_CH + 2 * cp + 1) << 14) + hw];
  xpad2[(size_t)pp * XPL + (y + 6) * XWP + (x + 6)] = pack2(a, bb);
}

// ---------------------------------------------------------------------------
// Fused bg sim + softmax + read. One block = 16x8 out px, one b, one scale.
// 512 thr = 8 waves. LDS: x-halo (pixel-major 32B/px) | att halo (128B/px,
// XOR (pix&7)<<4 swizzle) | A double-buffer 2x8KB.
// Sim: waves split att-halo N-tiles; K-loop over uvp (2uv x 16c), A dbuf'd.
// Softmax in-register (shfl over g). Read: wave w owns out row w, full
// K = P*P*64 in 4 ILP chains; A (hi/lo) LDS-staged 2 uv/chunk dbuf.
// ---------------------------------------------------------------------------
struct FusedArgs {
  const unsigned* xpad2;
  const _Float16* simA[3];    // si 0..2 = P7,P5,P3
  const _Float16* readA[3];
  float* fbgs[3];             // fbg + p*2*CHW
};

#define FX_ATT 17920
#define FX_ABUF 58880
#define FX_SMEM 75264

template<int P>
__device__ __forceinline__ void fused_body(
    const unsigned* __restrict__ xp,          // + b*8 planes
    const _Float16* __restrict__ simA,
    const _Float16* __restrict__ readA,
    float* __restrict__ fb,                   // fbgs + b*CHW
    unsigned char* smem, int tid, int x0, int y0)
{
  constexpr int PAD = P / 2;
  constexpr int THY = 8 + 2 * PAD, THX = 16 + 2 * PAD;  // att halo
  constexpr int XH = 8 + 4 * PAD, XW = 16 + 4 * PAD;    // x halo
  constexpr int NXP = XH * XW, NHP = THY * THX;
  constexpr int NT = (NHP + 15) / 16;
  constexpr int NUVP = (P * P + 1) / 2;
  constexpr int NCH = (P * P + 1) / 2;

  unsigned char* xbuf = smem;
  unsigned char* att  = smem + FX_ATT;
  unsigned char* abuf = smem + FX_ABUF;

  const int w = __builtin_amdgcn_readfirstlane(tid >> 6);
  const int lane = tid & 63;
  const int col = lane & 15, g = lane >> 4;

  // ---- stage x halo: [pix][16c] f16 ----
  const int oy = y0 - 2 * PAD + 6, ox = x0 - 2 * PAD + 6;
  for (int t = tid; t < NXP * 8; t += 512) {
    int cp = t / NXP, pix = t - cp * NXP;
    int ly = pix / XW, lx = pix - ly * XW;
    *(unsigned*)(xbuf + pix * 32 + cp * 4) =
        xp[(size_t)cp * XPL + (oy + ly) * XWP + (ox + lx)];
  }

  // ---- per-tile pixel coords (static-indexed) ----
  int ayv[3], axv[3];
#pragma unroll
  for (int ti = 0; ti < 3; ++ti) {
    int nt = w + ti * 8;
    int pix = nt * 16 + col;
    if (pix > NHP - 1) pix = NHP - 1;
    ayv[ti] = pix / THX;
    axv[ti] = pix - ayv[ti] * THX;
  }

  f32x4 acc[3][4];
#pragma unroll
  for (int ti = 0; ti < 3; ++ti)
#pragma unroll
    for (int mt = 0; mt < 4; ++mt) acc[ti][mt] = (f32x4){0.f, 0.f, 0.f, 0.f};

  // ---- sim K-loop over uvp, A double-buffered ----
  uint4 sreg = *((const uint4*)simA + tid);
  for (int uvp = 0; uvp < NUVP; ++uvp) {
    *((uint4*)(abuf + (uvp & 1) * 8192) + tid) = sreg;
    if (uvp + 1 < NUVP) sreg = *((const uint4*)(simA + (size_t)(uvp + 1) * 4096) + tid);
    __syncthreads();

    const unsigned char* ab = abuf + (uvp & 1) * 8192;
    f16x8 af[2][4];
#pragma unroll
    for (int s = 0; s < 2; ++s)
#pragma unroll
      for (int mt = 0; mt < 4; ++mt)
        af[s][mt] = *(const f16x8*)(ab + ((s * 4 + mt) << 10) + col * 64 +
                                    ((g ^ (col & 3)) << 4));

    int uva = 2 * uvp;
    int uvb = uva + 1; if (uvb >= P * P) uvb = uva;
    const int ua = uva / P, va = uva - ua * P;
    const int ub = uvb / P, vb = uvb - ub * P;
    const int u_ = (g >= 2) ? ub : ua;
    const int v_ = (g >= 2) ? vb : va;

#pragma unroll
    for (int ti = 0; ti < 3; ++ti) {
      int nt = w + ti * 8;
      if (nt < NT) {
        int xh = (ayv[ti] + u_) * XW + axv[ti] + v_;
        f16x8 bb = *(const f16x8*)(xbuf + xh * 32 + ((g & 1) << 4));
#pragma unroll
        for (int mt = 0; mt < 4; ++mt) {
          acc[ti][mt] = __builtin_amdgcn_mfma_f32_16x16x32_f16(af[0][mt], bb, acc[ti][mt], 0, 0, 0);
          acc[ti][mt] = __builtin_amdgcn_mfma_f32_16x16x32_f16(af[1][mt], bb, acc[ti][mt], 0, 0, 0);
        }
      }
    }
    __syncthreads();
  }

  // ---- softmax (over 64 m) + att store to LDS ----
#pragma unroll
  for (int ti = 0; ti < 3; ++ti) {
    int nt = w + ti * 8;
    if (nt < NT) {
      float l[16];
#pragma unroll
      for (int mt = 0; mt < 4; ++mt)
#pragma unroll
        for (int r = 0; r < 4; ++r) l[mt * 4 + r] = acc[ti][mt][r];
      float mx = l[0];
#pragma unroll
      for (int i = 1; i < 16; ++i) mx = fmaxf(mx, l[i]);
      mx = fmaxf(mx, __shfl_xor(mx, 16));
      mx = fmaxf(mx, __shfl_xor(mx, 32));
      float sum = 0.f;
#pragma unroll
      for (int i = 0; i < 16; ++i) { l[i] = __expf(l[i] - mx); sum += l[i]; }
      sum += __shfl_xor(sum, 16);
      sum += __shfl_xor(sum, 32);
      int pa = nt * 16 + col;
      int say = pa / THX, sax = pa - say * THX;
      int gy = y0 + say - PAD, gx = x0 + sax - PAD;
      bool inimg = (pa < NHP) & (gy >= 0) & (gy < Hdim) & (gx >= 0) & (gx < Wdim);
      float inv = inimg ? (1.f / sum) : 0.f;
      unsigned char* base = att + pa * 128;
      int swz = (pa & 7) << 4;
#pragma unroll
      for (int mt = 0; mt < 4; ++mt) {
        uint2 st = { pack2(l[mt * 4 + 0] * inv, l[mt * 4 + 1] * inv),
                     pack2(l[mt * 4 + 2] * inv, l[mt * 4 + 3] * inv) };
        *(uint2*)(base + ((mt * 32 + g * 8) ^ swz)) = st;
      }
    }
  }
  __syncthreads();   // att complete; abuf free for read weights

  // ---- read: wave w owns out row w; K = P*P*64, 4 acc chains ----
  f32x4 racc[4];
#pragma unroll
  for (int q = 0; q < 4; ++q) racc[q] = (f32x4){0.f, 0.f, 0.f, 0.f};

  uint4 rreg = *((const uint4*)readA + tid);
  for (int ch = 0; ch < NCH; ++ch) {
    *((uint4*)(abuf + (ch & 1) * 8192) + tid) = rreg;
    if (ch + 1 < NCH) rreg = *((const uint4*)(readA + (size_t)(ch + 1) * 4096) + tid);
    __syncthreads();
    const unsigned char* ab = abuf + (ch & 1) * 8192;
#pragma unroll
    for (int l = 0; l < 2; ++l) {
      int uv = 2 * ch + l;
      int uvc = (uv > P * P - 1) ? (P * P - 1) : uv;
      int u = uvc / P, v = uvc - u * P;
      int pix = (w + u) * THX + (col + v);
      int swz = (pix & 7) << 4;
#pragma unroll
      for (int ck = 0; ck < 2; ++ck) {
        f16x8 bb = *(const f16x8*)(att + pix * 128 + ((ck * 64 + g * 16) ^ swz));
        f16x8 ah = *(const f16x8*)(ab + ((l * 4 + ck * 2 + 0) * 16 + col) * 64 +
                                   ((g ^ (col & 3)) << 4));
        f16x8 al = *(const f16x8*)(ab + ((l * 4 + ck * 2 + 1) * 16 + col) * 64 +
                                   ((g ^ (col & 3)) << 4));
        racc[ck * 2 + 0] = __builtin_amdgcn_mfma_f32_16x16x32_f16(ah, bb, racc[ck * 2 + 0], 0, 0, 0);
        racc[ck * 2 + 1] = __builtin_amdgcn_mfma_f32_16x16x32_f16(al, bb, racc[ck * 2 + 1], 0, 0, 0);
      }
    }
    __syncthreads();
  }

  f32x4 s = racc[0] + racc[1] + racc[2] + racc[3];
  int gy = y0 + w, gx = x0 + col;
  int cy = min(P - 1, gy + PAD) - max(0, gy + PAD - (Hdim - 1)) + 1;
  int cx = min(P - 1, gx + PAD) - max(0, gx + PAD - (Wdim - 1)) + 1;
  float inv = 1.f / ((float)(cy * cx) + 1e-8f);
  float* outp = fb + (size_t)(g * 4) * HWdim + gy * Wdim + gx;
#pragma unroll
  for (int r = 0; r < 4; ++r)
    outp[(size_t)r * HWdim] = s[r] * inv;
}

__global__ __launch_bounds__(512, 4) void k_fused(FusedArgs a) {
  __shared__ __align__(16) unsigned char smem[FX_SMEM];
  const int z = blockIdx.z, si = z >> 1, b = z & 1;
  const unsigned* xp = a.xpad2 + (size_t)(b * 8) * XPL;
  const int x0 = blockIdx.x * 16, y0 = blockIdx.y * 8;
  if (si == 0)
    fused_body<7>(xp, a.simA[0], a.readA[0], a.fbgs[0] + (size_t)b * CHW, smem, threadIdx.x, x0, y0);
  else if (si == 1)
    fused_body<5>(xp, a.simA[1], a.readA[1], a.fbgs[1] + (size_t)b * CHW, smem, threadIdx.x, x0, y0);
  else
    fused_body<3>(xp, a.simA[2], a.readA[2], a.fbgs[2] + (size_t)b * CHW, smem, threadIdx.x, x0, y0);
}

// ---------------------------------------------------------------------------
// tg sim: VALU (M=8). 8x8 tile, 512 thr, grid (16,16,6): z = si*2 + b.
// ---------------------------------------------------------------------------
template<int P>
__device__ __forceinline__ void sim_core_tg(
    const unsigned* __restrict__ xt2, float* __restrict__ red,
    const float* __restrict__ memT, unsigned* __restrict__ att2,
    int wv, int lane, int x0, int y0)
{
  constexpr int TH = 8 + P - 1, SR = SimSR<P>::v;
  constexpr int M = 8;
  const int px = lane & 7, py = lane >> 3;
  const int cp = wv;
  v2f acc2[4];
#pragma unroll
  for (int mm = 0; mm < 4; ++mm) acc2[mm] = (v2f){0.f, 0.f};

#pragma unroll
  for (int i = 0; i < P; ++i) {
#pragma unroll
    for (int j = 0; j < P; ++j) {
      v2f vp = unpack2(xt2[(cp * TH + py + i) * SR + (px + j)]);
      const v2f* w0 = (const v2f*)(memT + (size_t)((((2 * cp) * P + i) * P + j)) * M);
      const v2f* w1 = (const v2f*)(memT + (size_t)((((2 * cp + 1) * P + i) * P + j)) * M);
      v2f v0 = {vp.x, vp.x}, v1 = {vp.y, vp.y};
#pragma unroll
      for (int mm = 0; mm < 4; ++mm) {
        acc2[mm] = __builtin_elementwise_fma(v0, w0[mm], acc2[mm]);
        acc2[mm] = __builtin_elementwise_fma(v1, w1[mm], acc2[mm]);
      }
    }
  }

#pragma unroll
  for (int mm = 0; mm < 4; ++mm) {
    red[(wv * 8 + 2 * mm) * 64 + lane]     = acc2[mm].x;
    red[(wv * 8 + 2 * mm + 1) * 64 + lane] = acc2[mm].y;
  }
  __syncthreads();

  float lg[8];
#pragma unroll
  for (int m = 0; m < 8; ++m) {
    float s = red[m * 64 + lane];
#pragma unroll
    for (int w = 1; w < 8; ++w) s += red[(w * 8 + m) * 64 + lane];
    lg[m] = s;
  }
  float gm = lg[0];
#pragma unroll
  for (int m = 1; m < 8; ++m) gm = fmaxf(gm, lg[m]);
  float tot = 0.f;
#pragma unroll
  for (int m = 0; m < 8; ++m) { lg[m] = __expf(lg[m] - gm); tot += lg[m]; }
  float inv = 1.f / tot;

  const int gy = y0 + py, gx = x0 + px;
  if (wv < 4)
    att2[(size_t)wv * PL + (gy + 3) * WP + (gx + 3)] =
        pack2(lg[2 * wv] * inv, lg[2 * wv + 1] * inv);
}

struct SimTgArgs {
  const unsigned* xpad2;
  const float* memT[3];      // si 0..2 = P7,P5,P3
  unsigned* atttg[3];
};

template<int P>
__device__ __forceinline__ void sim_tg_scale(
    const unsigned* __restrict__ xp, const float* __restrict__ memT,
    unsigned* __restrict__ att2, unsigned* xt2, float* red,
    int tid, int x0, int y0)
{
  constexpr int PAD = P / 2, TH = 8 + P - 1, SR = SimSR<P>::v;
  const int wv = __builtin_amdgcn_readfirstlane(tid >> 6);
  const int lane = tid & 63;
  const int oy = y0 + 6 - PAD, ox = x0 + 6 - PAD;
  for (int t = tid; t < 8 * TH * TH; t += 512) {
    int cp = t / (TH * TH);
    int r = t - cp * (TH * TH);
    int ly = r / TH, lx = r - ly * TH;
    xt2[(cp * TH + ly) * SR + lx] = xp[(size_t)cp * XPL + (oy + ly) * XWP + ox + lx];
  }
  __syncthreads();
  sim_core_tg<P>(xt2, red, memT, att2, wv, lane, x0, y0);
}

__global__ __launch_bounds__(512, 8) void k_simtg(SimTgArgs a) {
  __shared__ unsigned xt2[2240];
  __shared__ float red[4096];
  const int z = blockIdx.z, si = z >> 1, b = z & 1;
  const unsigned* xp = a.xpad2 + (size_t)((2 + b) * 8) * XPL;
  unsigned* att = a.atttg[si] + (size_t)(b * 4) * PL;
  const int x0 = blockIdx.x * 8, y0 = blockIdx.y * 8;
  if (si == 0)      sim_tg_scale<7>(xp, a.memT[0], att, xt2, red, threadIdx.x, x0, y0);
  else if (si == 1) sim_tg_scale<5>(xp, a.memT[1], att, xt2, red, threadIdx.x, x0, y0);
  else              sim_tg_scale<3>(xp, a.memT[2], att, xt2, red, threadIdx.x, x0, y0);
}

// ---------------------------------------------------------------------------
// tg read: VALU. 16x8 tile, 512 thr, grid (8,16,6): z = si*2 + b.
// ---------------------------------------------------------------------------
struct ReadTgArgs {
  const unsigned* atttg[3];
  const float* memRtg[3];
  float* ftgs[3];
};

template<int P>
__device__ __forceinline__ void read_tg_body(
    const unsigned* __restrict__ attp, const float* __restrict__ memRtg,
    float* __restrict__ ftg_b, float* atf, int tid, int x0, int y0)
{
  constexpr int PAD = P / 2;
  constexpr int THY = 8 + P - 1, THX = 16 + P - 1;
  constexpr int SR = 25;
  const int oy = y0 + 3 - PAD, ox = x0 + 3 - PAD;
  for (int t = tid; t < 4 * THY * THX; t += 512) {
    int mp = t / (THY * THX);
    int r = t - mp * (THY * THX);
    int ly = r / THX, lx = r - ly * THX;
    v2f v = unpack2(attp[(size_t)mp * PL + (oy + ly) * WP + ox + lx]);
    atf[((2 * mp) * THY + ly) * SR + lx]     = v.x;
    atf[((2 * mp + 1) * THY + ly) * SR + lx] = v.y;
  }
  __syncthreads();

  const int h = tid >> 7, pix = tid & 127;
  const int px = pix & 15, py = pix >> 4;
  v2f acc2[2];
#pragma unroll
  for (int q = 0; q < 2; ++q) acc2[q] = (v2f){0.f, 0.f};

  for (int ml = 0; ml < 8; ++ml) {
    const float* atm = atf + ml * THY * SR;
    const float* wbase = memRtg + (size_t)(ml * P * P) * C_CH;
#pragma unroll
    for (int u = 0; u < P; ++u) {
      const float* ar = atm + (py + u) * SR + px;
#pragma unroll
      for (int vv = 0; vv < P; ++vv) {
        float val = ar[vv];
        const v2f* wr = (const v2f*)(wbase + (u * P + vv) * C_CH) + h * 2;
        v2f vvv = {val, val};
#pragma unroll
        for (int q = 0; q < 2; ++q)
          acc2[q] = __builtin_elementwise_fma(vvv, wr[q], acc2[q]);
      }
    }
  }

  int gy = y0 + py, gx = x0 + px;
  int cy = min(P - 1, gy + PAD) - max(0, gy + PAD - (Hdim - 1)) + 1;
  int cx = min(P - 1, gx + PAD) - max(0, gx + PAD - (Wdim - 1)) + 1;
  float inv = 1.f / ((float)(cy * cx) + 1e-8f);
  float* outp = ftg_b + gy * Wdim + gx;
#pragma unroll
  for (int q = 0; q < 2; ++q) {
    int cp = h * 2 + q;
    outp[(size_t)(2 * cp) * HWdim]     = acc2[q].x * inv;
    outp[(size_t)(2 * cp + 1) * HWdim] = acc2[q].y * inv;
  }
}

__global__ __launch_bounds__(512, 8) void k_readtg(ReadTgArgs a) {
  __shared__ float atf[8 * 14 * 25];
  const int z = blockIdx.z, si = z >> 1, b = z & 1;
  const int x0 = blockIdx.x * 16, y0 = blockIdx.y * 8;
  if (si == 0)
    read_tg_body<7>(a.atttg[0] + (size_t)(b * 4) * PL, a.memRtg[0],
                    a.ftgs[0] + (size_t)b * CHW, atf, threadIdx.x, x0, y0);
  else if (si == 1)
    read_tg_body<5>(a.atttg[1] + (size_t)(b * 4) * PL, a.memRtg[1],
                    a.ftgs[1] + (size_t)b * CHW, atf, threadIdx.x, x0, y0);
  else
    read_tg_body<3>(a.atttg[2] + (size_t)(b * 4) * PL, a.memRtg[2],
                    a.ftgs[2] + (size_t)b * CHW, atf, threadIdx.x, x0, y0);
}

// ---------------------------------------------------------------------------
// pooled[br*32 + b*16 + c] = mean over pixels of sum over 3 scale-slabs
// ---------------------------------------------------------------------------
__global__ __launch_bounds__(256) void k_pool(const float* __restrict__ fbg,
                                              const float* __restrict__ ftg,
                                              float* __restrict__ pooled)
{
  __shared__ float red[256];
  int i = blockIdx.x;                       // 64
  int br = i >> 5, b = (i >> 4) & 1, c = i & 15;
  const float* base = (br ? ftg : fbg) + (size_t)b * CHW + (size_t)c * HWdim;
  float s = 0.f;
  for (int t = threadIdx.x; t < HWdim; t += 256)
    s += base[t] + base[(size_t)2 * CHW + t] + base[(size_t)4 * CHW + t];
  red[threadIdx.x] = s;
  __syncthreads();
  for (int off = 128; off > 0; off >>= 1) {
    if ((int)threadIdx.x < off) red[threadIdx.x] += red[threadIdx.x + off];
    __syncthreads();
  }
  if (threadIdx.x == 0) pooled[br * 32 + b * 16 + c] = red[0] * (1.f / (float)HWdim);
}

// ---------------------------------------------------------------------------
// Fusion MLP + softmax weights
// ---------------------------------------------------------------------------
__global__ __launch_bounds__(128) void k_mlp(
    const float* __restrict__ pooled,
    const float* __restrict__ w1b, const float* __restrict__ b1b,
    const float* __restrict__ w2b, const float* __restrict__ b2b,
    const float* __restrict__ w1t, const float* __restrict__ b1t,
    const float* __restrict__ w2t, const float* __restrict__ b2t,
    float* __restrict__ wt)
{
  __shared__ float hdn[Bdim][4];
  __shared__ float lg[Bdim][48];
  int t = threadIdx.x;
  for (int br = 0; br < 2; ++br) {
    const float* w1 = br ? w1t : w1b;
    const float* b1 = br ? b1t : b1b;
    const float* w2 = br ? w2t : w2b;
    const float* b2 = br ? b2t : b2b;
    if (t < 8) {
      int b = t >> 2, h = t & 3;
      float s = b1[h];
      for (int c = 0; c < C_CH; ++c) s += pooled[br * 32 + b * 16 + c] * w1[h * 16 + c];
      hdn[b][h] = fmaxf(s, 0.f);
    }
    __syncthreads();
    if (t < 96) {
      int b = t / 48, j = t - b * 48;
      float s = b2[j];
      for (int h = 0; h < 4; ++h) s += hdn[b][h] * w2[j * 4 + h];
      lg[b][j] = s;
    }
    __syncthreads();
    if (t < 32) {
      int b = t >> 4, c = t & 15;
      float l0 = lg[b][c], l1 = lg[b][16 + c], l2 = lg[b][32 + c];
      float m = fmaxf(l0, fmaxf(l1, l2));
      float e0 = __expf(l0 - m), e1 = __expf(l1 - m), e2 = __expf(l2 - m);
      float inv = 1.f / (e0 + e1 + e2);
      wt[((br * 2 + b) * 3 + 0) * 16 + c] = e0 * inv;
      wt[((br * 2 + b) * 3 + 1) * 16 + c] = e1 * inv;
      wt[((br * 2 + b) * 3 + 2) * 16 + c] = e2 * inv;
    }
    __syncthreads();
  }
}

__global__ __launch_bounds__(256) void k_out(const float* __restrict__ fbg,
                                             const float* __restrict__ ftg,
                                             const float* __restrict__ wt,
                                             float* __restrict__ out)
{
  int idx = blockIdx.x * 256 + threadIdx.x;      // 0 .. 2*PAIR_ELEMS-1
  int br  = idx >> 19;
  int rem = idx & ((1 << 19) - 1);
  int b   = rem >> 18;
  int off = rem & ((1 << 18) - 1);
  int c   = off >> 14;
  const float* f = (br == 0) ? fbg : ftg;
  int wbase = (br * 2 + b) * 3;
  float acc = 0.f;
#pragma unroll
  for (int s = 0; s < 3; ++s) {
    float v = f[(size_t)(s * 2 + b) * CHW + off];
    acc = fmaf(wt[(wbase + s) * 16 + c], v, acc);
  }
  out[idx] = acc;
}

// ---------------------------------------------------------------------------
extern "C" void kernel_launch(void* const* d_in, const int* in_sizes, int n_in,
                              void* d_out, int out_size, void* d_ws, size_t ws_size,
                              hipStream_t stream)
{
  const float* bg = (const float*)d_in[0];
  const float* tg = (const float*)d_in[1];
  const float* bg_mem[3]  = {(const float*)d_in[2],  (const float*)d_in[6],  (const float*)d_in[10]};
  const float* tg_mem[3]  = {(const float*)d_in[3],  (const float*)d_in[7],  (const float*)d_in[11]};
  const float* bg_temp[3] = {(const float*)d_in[4],  (const float*)d_in[8],  (const float*)d_in[12]};
  const float* tg_temp[3] = {(const float*)d_in[5],  (const float*)d_in[9],  (const float*)d_in[13]};
  const float* bg_fc1_w = (const float*)d_in[14];
  const float* bg_fc1_b = (const float*)d_in[15];
  const float* bg_fc2_w = (const float*)d_in[16];
  const float* bg_fc2_b = (const float*)d_in[17];
  const float* tg_fc1_w = (const float*)d_in[18];
  const float* tg_fc1_b = (const float*)d_in[19];
  const float* tg_fc2_w = (const float*)d_in[20];
  const float* tg_fc2_b = (const float*)d_in[21];

  float* ws = (float*)d_ws;
  unsigned* xpad2  = (unsigned*)ws;                          // 32 * XPL   = 627,200
  unsigned* atttgB = xpad2 + (size_t)32 * XPL;               // 24 * PL    = 437,376
  float*    pooled = (float*)(atttgB + (size_t)24 * PL);     // 64
  float*    wt     = pooled + 64;                            // 192
  _Float16* simA   = (_Float16*)(wt + 192);                  // 176,128 halfs
  _Float16* readA  = simA + 176128;                          // 176,128 halfs
  float*    memT   = (float*)(readA + 176128);               // 95,616
  float*    memRtg = memT + 95616;                           // 10,624
  float*    ftg    = memRtg + 10624;                         // 6*CHW
  float*    fbg    = ftg + (size_t)6 * CHW;                  // 6*CHW

  // zero xpad2 + atttg (borders) + pooled/wt + simA + readA in one shot
  // = 627,200 + 437,376 + 256 + 88,064 + 88,064 = 1,240,960 u32
  hipMemsetAsync(xpad2, 0, (size_t)1240960 * 4, stream);

  const int   Ms[6] = {64, 64, 64, 8, 8, 8};
  const int   Ps[6] = {3, 5, 7, 3, 5, 7};
  const float* mems[6]  = {bg_mem[0], bg_mem[1], bg_mem[2], tg_mem[0], tg_mem[1], tg_mem[2]};
  const float* temps[6] = {bg_temp[0], bg_temp[1], bg_temp[2], tg_temp[0], tg_temp[1], tg_temp[2]};

  float* memTs[6];
  const size_t aOff[3] = {0, 102400, 155648};   // si 0..2 = P7,P5,P3 (halfs)
  size_t offT = 0;
  const size_t offRtg[3] = {0, 1152, 4352};     // PS order (P3,P5,P7)
  PrepArgs pa;
  for (int k = 0; k < 6; ++k) {
    int D = C_CH * Ps[k] * Ps[k];
    memTs[k] = memT + offT;
    if (k < 3) {
      int si = 2 - k;                           // PS k -> scale index
      pa.d[k] = {mems[k], temps[k], memTs[k], nullptr,
                 simA + aOff[si], readA + aOff[si], Ms[k], D, Ps[k]};
    } else {
      pa.d[k] = {mems[k], temps[k], memTs[k], memRtg + offRtg[k - 3],
                 nullptr, nullptr, Ms[k], D, Ps[k]};
    }
    offT += (size_t)Ms[k] * D;
  }
  k_prep<<<dim3(196, 6), 256, 0, stream>>>(pa);
  k_padx<<<2048, 256, 0, stream>>>(bg, tg, xpad2);

  SimTgArgs sta;
  sta.xpad2 = xpad2;
  sta.memT[0] = memTs[5]; sta.memT[1] = memTs[4]; sta.memT[2] = memTs[3];
  FusedArgs fa;
  fa.xpad2 = xpad2;
  ReadTgArgs rta;
  for (int si = 0; si < 3; ++si) {
    int p = 2 - si;
    fa.simA[si]  = simA + aOff[si];
    fa.readA[si] = readA + aOff[si];
    fa.fbgs[si]  = fbg + (size_t)p * 2 * CHW;
    sta.atttg[si] = atttgB + (size_t)si * 8 * PL;
    rta.atttg[si] = atttgB + (size_t)si * 8 * PL;
    rta.memRtg[si] = memRtg + offRtg[p];
    rta.ftgs[si]   = ftg + (size_t)p * 2 * CHW;
  }

  k_simtg<<<dim3(16, 16, 6), 512, 0, stream>>>(sta);
  k_fused<<<dim3(8, 16, 6), 512, 0, stream>>>(fa);
  k_readtg<<<dim3(8, 16, 6), 512, 0, stream>>>(rta);

  k_pool<<<64, 256, 0, stream>>>(fbg, ftg, pooled);
  k_mlp<<<1, 128, 0, stream>>>(pooled, bg_fc1_w, bg_fc1_b, bg_fc2_w, bg_fc2_b,
                               tg_fc1_w, tg_fc1_b, tg_fc2_w, tg_fc2_b, wt);
  k_out<<<(2 * PAIR_ELEMS) / 256, 256, 0, stream>>>(fbg, ftg, wt, (float*)d_out);
}

// Round 5
// 176.953 us; speedup vs baseline: 1.3492x; 1.3492x over previous
//
#include <hip/hip_runtime.h>

#define C_CH 16
#define Hdim 128
#define Wdim 128
#define HWdim 16384
#define CHW (C_CH * HWdim)                 // 262144 floats: one [C][H][W] slab
#define Bdim 2
#define PAIR_ELEMS (Bdim * CHW)            // 524288

// x canvas: border 6 (= 2*max PAD, fused kernel needs double halo)
#define XWP 140
#define XHP 140
#define XPL (XHP * XWP)                    // 19600 per pair-plane

typedef float v2f __attribute__((ext_vector_type(2)));
typedef _Float16 h2 __attribute__((ext_vector_type(2)));
typedef _Float16 f16x8 __attribute__((ext_vector_type(8)));
typedef float f32x4 __attribute__((ext_vector_type(4)));

__device__ __forceinline__ unsigned pack2(float a, float b) {
  h2 h = {(_Float16)a, (_Float16)b};
  return __builtin_bit_cast(unsigned, h);
}
__device__ __forceinline__ void gadd(float* p, float v) {
  __hip_atomic_fetch_add(p, v, __ATOMIC_RELAXED, __HIP_MEMORY_SCOPE_AGENT);
}

// ---------------------------------------------------------------------------
// Prep (all MFMA A-operand layouts, hi+lo f16 split for fp32-accurate weights)
// bg simA  [uvp][s(2)][mt(4)][row16][k32 swz]   scaled   (chunk 8KB)
// bg readA [uvf][ck(2)][s(2)][c16][k32 swz]     unscaled (chunk 8KB = 2 uv)
// tg simA  [uvp][s(2)][row16(m<8)][k32 swz]     scaled   (chunk 2KB)
// tg readA [ch][s(2)][c16][k32 swz] k=q*8+m, uv=4ch+q    (chunk 2KB)
// k-swizzle: halfs offset (kg ^ (row&3))*8 + kl
// ---------------------------------------------------------------------------
struct PrepDesc {
  const float* mem;
  const float* temp;
  _Float16* simA;
  _Float16* readA;
  int M, D, P, tg;
};
struct PrepArgs { PrepDesc d[6]; };

__global__ __launch_bounds__(256) void k_prep(PrepArgs a) {
  PrepDesc de = a.d[blockIdx.y];
  int n = de.M * de.D;
  int idx = blockIdx.x * 256 + threadIdx.x;
  if (idx >= n) return;
  int m = idx / de.D;
  int d = idx - m * de.D;
  float val = de.mem[idx];
  float sc = de.temp[0] / sqrtf((float)de.D);
  int pp = de.P * de.P;
  int c = d / pp;
  int r = d - c * pp;
  int i = r / de.P;
  int j = r - i * de.P;
  int uv = i * de.P + j;                 // unflipped (sim correlation)
  int uvp = uv >> 1, luv = uv & 1;
  int kk = luv * 16 + c, kg = kk >> 3, kl = kk & 7;
  int u = de.P - 1 - i, v = de.P - 1 - j;
  int uvf = u * de.P + v;                // flipped (read fold)
  float sv = val * sc;
  if (!de.tg) {
    int mt = m >> 4, row = m & 15;
    _Float16 hi = (_Float16)sv;
    size_t bi = ((size_t)uvp * 8 + mt) * 512 + row * 32 +
                (size_t)((kg ^ (row & 3)) * 8 + kl);
    de.simA[bi] = hi;
    de.simA[bi + 2048] = (_Float16)(sv - (float)hi);
    int ck = m >> 5, m5 = m & 31, kg2 = m5 >> 3, kl2 = m5 & 7;
    _Float16 hr = (_Float16)val;
    size_t b2 = (size_t)uvf * 2048 + (size_t)(ck * 2) * 512 + c * 32 +
                (size_t)((kg2 ^ (c & 3)) * 8 + kl2);
    de.readA[b2] = hr;
    de.readA[b2 + 512] = (_Float16)(val - (float)hr);
  } else {
    _Float16 hi = (_Float16)sv;          // m in 0..7, rows 8..15 stay zero
    size_t bi = (size_t)(uvp * 2) * 512 + m * 32 +
                (size_t)((kg ^ (m & 3)) * 8 + kl);
    de.simA[bi] = hi;
    de.simA[bi + 512] = (_Float16)(sv - (float)hi);
    int ch = uvf >> 2, q = uvf & 3;
    _Float16 hr = (_Float16)val;
    size_t b2 = (size_t)ch * 1024 + c * 32 +
                (size_t)((q ^ (c & 3)) * 8 + (m & 7));
    de.readA[b2] = hr;
    de.readA[b2 + 512] = (_Float16)(val - (float)hr);
  }
}

// ---------------------------------------------------------------------------
// Build f16 c-pair-packed padded canvas (border 6).
// ---------------------------------------------------------------------------
__global__ __launch_bounds__(256) void k_padx(const float* __restrict__ bg,
                                              const float* __restrict__ tg,
                                              unsigned* __restrict__ xpad2)
{
  int idx = blockIdx.x * 256 + threadIdx.x;     // 32 pair-planes * HW
  int pp = idx >> 14;
  int hw = idx & (HWdim - 1);
  int y = hw >> 7, x = hw & 127;
  int z = pp >> 3, cp = pp & 7;
  const float* src = (z < 2) ? bg : tg;
  int b = z & 1;
  float a = src[((b * C_CH + 2 * cp) << 14) + hw];
  float bb = src[((b * C_CH + 2 * cp + 1) << 14) + hw];
  xpad2[(size_t)pp * XPL + (y + 6) * XWP + (x + 6)] = pack2(a, bb);
}

// ---------------------------------------------------------------------------
// Fully fused sim + softmax + read (+ pooled partial) for bg AND tg.
// Block = 16x8 out px, one b, one scale, one branch. 512 thr = 8 waves.
// LDS: xbuf [2 half][NXP][16B] | att (bg 128B/px swz, tg 16B/px) | A dbuf.
// Single barrier per double-buffered A chunk.
// z: 0..5 bg (si*2+b), 6..11 tg. si 0..2 = {P7,P5,P3}.
// ---------------------------------------------------------------------------
struct FusedArgs {
  const unsigned* xpad2;
  const _Float16* simA[3];
  const _Float16* readA[3];
  const _Float16* simAtg[3];
  const _Float16* readAtg[3];
  float* fbgs[3];
  float* ftgs[3];
  float* pooled;
};

#define FX_ATT 17920
#define FX_ABUF 58880
#define FX_SMEM 75264

template<int P, bool BG>
__device__ __forceinline__ void fused_body(
    const unsigned* __restrict__ xp,          // + plane base
    const _Float16* __restrict__ simA,
    const _Float16* __restrict__ readA,
    float* __restrict__ fout,                 // + b*CHW
    float* __restrict__ poolp,                // pooled + branch/b base
    unsigned char* smem, int tid, int x0, int y0)
{
  constexpr int PAD = P / 2;
  constexpr int THY = 8 + 2 * PAD, THX = 16 + 2 * PAD;  // att halo
  constexpr int XH = 8 + 4 * PAD, XW = 16 + 4 * PAD;    // x halo
  constexpr int NXP = XH * XW, NHP = THY * THX;
  constexpr int NT = (NHP + 15) / 16;
  constexpr int NUVP = (P * P + 1) / 2;
  constexpr int NCH = BG ? (P * P + 1) / 2 : (P * P + 3) / 4;
  constexpr int NMT = BG ? 4 : 1;
  constexpr int SCHB = BG ? 8192 : 2048;     // sim A chunk bytes
  constexpr int RCHB = BG ? 8192 : 2048;     // read A chunk bytes
  constexpr int SLD = SCHB / 16, RLD = RCHB / 16;
  constexpr int NRACC = BG ? 4 : 2;

  unsigned char* xbuf = smem;
  unsigned char* att  = smem + FX_ATT;
  unsigned char* abuf = smem + FX_ABUF;

  const int w = __builtin_amdgcn_readfirstlane(tid >> 6);
  const int lane = tid & 63;
  const int col = lane & 15, g = lane >> 4;

  // ---- stage x halo as [h][pix][16B] (c = h*8..h*8+7), b128 writes ----
  const int oy = y0 - 2 * PAD + 6, ox = x0 - 2 * PAD + 6;
  for (int t = tid; t < 2 * NXP; t += 512) {
    int h = (t >= NXP) ? 1 : 0;
    int pix = t - h * NXP;
    int ly = pix / XW, lx = pix - ly * XW;
    const unsigned* s = xp + (size_t)(h * 4) * XPL + (oy + ly) * XWP + (ox + lx);
    uint4 vv = { s[0], s[XPL], s[2 * XPL], s[3 * XPL] };
    *(uint4*)(xbuf + (h * NXP + pix) * 16) = vv;
  }

  // ---- per-tile pixel coords ----
  int ayv[3], axv[3];
#pragma unroll
  for (int ti = 0; ti < 3; ++ti) {
    int nt = w + ti * 8;
    int pix = nt * 16 + col;
    if (pix > NHP - 1) pix = NHP - 1;
    ayv[ti] = pix / THX;
    axv[ti] = pix - ayv[ti] * THX;
  }

  f32x4 acc[3][NMT];
#pragma unroll
  for (int ti = 0; ti < 3; ++ti)
#pragma unroll
    for (int mt = 0; mt < NMT; ++mt) acc[ti][mt] = (f32x4){0.f, 0.f, 0.f, 0.f};

  // ---- sim K-loop, single-barrier double buffer ----
  uint4 sreg;
  if (tid < SLD) sreg = *((const uint4*)simA + tid);
  for (int uvp = 0; uvp < NUVP; ++uvp) {
    if (tid < SLD) {
      *((uint4*)(abuf + (uvp & 1) * 8192) + tid) = sreg;
      if (uvp + 1 < NUVP)
        sreg = *((const uint4*)(simA + (size_t)(uvp + 1) * (SCHB / 2)) + tid);
    }
    __syncthreads();

    const unsigned char* ab = abuf + (uvp & 1) * 8192;
    f16x8 af[2][NMT];
#pragma unroll
    for (int s = 0; s < 2; ++s)
#pragma unroll
      for (int mt = 0; mt < NMT; ++mt)
        af[s][mt] = *(const f16x8*)(ab + (s * NMT + mt) * 1024 + col * 64 +
                                    ((g ^ (col & 3)) << 4));

    int uva = 2 * uvp;
    int uvb = uva + 1; if (uvb >= P * P) uvb = uva;   // pad slot: zero A
    const int ua = uva / P, va = uva - ua * P;
    const int ub = uvb / P, vb = uvb - ub * P;
    const int u_ = (g >= 2) ? ub : ua;
    const int v_ = (g >= 2) ? vb : va;

#pragma unroll
    for (int ti = 0; ti < 3; ++ti) {
      int nt = w + ti * 8;
      if (nt < NT) {
        int xpix = (ayv[ti] + u_) * XW + axv[ti] + v_;
        f16x8 bb = *(const f16x8*)(xbuf + ((g & 1) * NXP + xpix) * 16);
#pragma unroll
        for (int mt = 0; mt < NMT; ++mt) {
          acc[ti][mt] = __builtin_amdgcn_mfma_f32_16x16x32_f16(af[0][mt], bb, acc[ti][mt], 0, 0, 0);
          acc[ti][mt] = __builtin_amdgcn_mfma_f32_16x16x32_f16(af[1][mt], bb, acc[ti][mt], 0, 0, 0);
        }
      }
    }
  }

  // prefetch first read-A chunk early
  uint4 rreg;
  if (tid < RLD) rreg = *((const uint4*)readA + tid);

  // ---- softmax + att store to LDS ----
#pragma unroll
  for (int ti = 0; ti < 3; ++ti) {
    int nt = w + ti * 8;
    if (nt < NT) {
      int pa = nt * 16 + col;
      int say = pa / THX, sax = pa - say * THX;
      int gy = y0 + say - PAD, gx = x0 + sax - PAD;
      bool inimg = (pa < NHP) & (gy >= 0) & (gy < Hdim) & (gx >= 0) & (gx < Wdim);
      if constexpr (BG) {
        float l[16];
#pragma unroll
        for (int mt = 0; mt < 4; ++mt)
#pragma unroll
          for (int r = 0; r < 4; ++r) l[mt * 4 + r] = acc[ti][mt][r];
        float mx = l[0];
#pragma unroll
        for (int i2 = 1; i2 < 16; ++i2) mx = fmaxf(mx, l[i2]);
        mx = fmaxf(mx, __shfl_xor(mx, 16));
        mx = fmaxf(mx, __shfl_xor(mx, 32));
        float sum = 0.f;
#pragma unroll
        for (int i2 = 0; i2 < 16; ++i2) { l[i2] = __expf(l[i2] - mx); sum += l[i2]; }
        sum += __shfl_xor(sum, 16);
        sum += __shfl_xor(sum, 32);
        float inv = inimg ? (1.f / sum) : 0.f;
        unsigned char* base = att + pa * 128;
        int swz = (pa & 7) << 4;
#pragma unroll
        for (int mt = 0; mt < 4; ++mt) {
          uint2 st = { pack2(l[mt * 4 + 0] * inv, l[mt * 4 + 1] * inv),
                       pack2(l[mt * 4 + 2] * inv, l[mt * 4 + 3] * inv) };
          *(uint2*)(base + ((mt * 32 + g * 8) ^ swz)) = st;
        }
      } else {
        float l0 = acc[ti][0][0], l1 = acc[ti][0][1];
        float l2 = acc[ti][0][2], l3 = acc[ti][0][3];
        float mx = fmaxf(fmaxf(l0, l1), fmaxf(l2, l3));
        mx = fmaxf(mx, __shfl_xor(mx, 16));      // g0<->g1 (m 0..7)
        l0 = __expf(l0 - mx); l1 = __expf(l1 - mx);
        l2 = __expf(l2 - mx); l3 = __expf(l3 - mx);
        float sum = l0 + l1 + l2 + l3;
        sum += __shfl_xor(sum, 16);
        float inv = inimg ? (1.f / sum) : 0.f;
        if (g < 2) {                              // m = g*4 + r
          uint2 st = { pack2(l0 * inv, l1 * inv), pack2(l2 * inv, l3 * inv) };
          *(uint2*)(att + pa * 16 + g * 8) = st;
        }
      }
    }
  }
  __syncthreads();   // att complete; all sim abuf reads done

  // ---- read phase: wave w owns out row w ----
  f32x4 racc[NRACC];
#pragma unroll
  for (int q = 0; q < NRACC; ++q) racc[q] = (f32x4){0.f, 0.f, 0.f, 0.f};

  for (int ch = 0; ch < NCH; ++ch) {
    if (tid < RLD) {
      *((uint4*)(abuf + (ch & 1) * 8192) + tid) = rreg;
      if (ch + 1 < NCH)
        rreg = *((const uint4*)(readA + (size_t)(ch + 1) * (RCHB / 2)) + tid);
    }
    __syncthreads();
    const unsigned char* ab = abuf + (ch & 1) * 8192;
    if constexpr (BG) {
#pragma unroll
      for (int l = 0; l < 2; ++l) {
        int uv = 2 * ch + l;
        int uvc = (uv > P * P - 1) ? (P * P - 1) : uv;
        int u = uvc / P, v = uvc - u * P;
        int pix = (w + u) * THX + (col + v);
        int swz = (pix & 7) << 4;
#pragma unroll
        for (int ck = 0; ck < 2; ++ck) {
          f16x8 bb = *(const f16x8*)(att + pix * 128 + ((ck * 64 + g * 16) ^ swz));
          f16x8 ah = *(const f16x8*)(ab + (l * 4 + ck * 2 + 0) * 1024 + col * 64 +
                                     ((g ^ (col & 3)) << 4));
          f16x8 al = *(const f16x8*)(ab + (l * 4 + ck * 2 + 1) * 1024 + col * 64 +
                                     ((g ^ (col & 3)) << 4));
          racc[ck * 2 + 0] = __builtin_amdgcn_mfma_f32_16x16x32_f16(ah, bb, racc[ck * 2 + 0], 0, 0, 0);
          racc[ck * 2 + 1] = __builtin_amdgcn_mfma_f32_16x16x32_f16(al, bb, racc[ck * 2 + 1], 0, 0, 0);
        }
      }
    } else {
      int uv = 4 * ch + g;                        // lane's g = K-slot q
      if (uv > P * P - 1) uv = P * P - 1;         // pad: zero A rows
      int u = uv / P, v = uv - u * P;
      int pix = (w + u) * THX + (col + v);
      f16x8 bb = *(const f16x8*)(att + pix * 16);
      int aoff = col * 64 + ((g ^ (col & 3)) << 4);
      f16x8 ah = *(const f16x8*)(ab + aoff);
      f16x8 al = *(const f16x8*)(ab + 1024 + aoff);
      racc[0] = __builtin_amdgcn_mfma_f32_16x16x32_f16(ah, bb, racc[0], 0, 0, 0);
      racc[1] = __builtin_amdgcn_mfma_f32_16x16x32_f16(al, bb, racc[1], 0, 0, 0);
    }
  }

  // ---- epilogue: divisor + store + pooled partial ----
  f32x4 sv;
  if constexpr (BG) sv = (racc[0] + racc[1]) + (racc[2] + racc[3]);
  else              sv = racc[0] + racc[1];
  int gy = y0 + w, gx = x0 + col;
  int cy = min(P - 1, gy + PAD) - max(0, gy + PAD - (Hdim - 1)) + 1;
  int cx = min(P - 1, gx + PAD) - max(0, gx + PAD - (Wdim - 1)) + 1;
  float inv = 1.f / ((float)(cy * cx) + 1e-8f);
  float o0 = sv[0] * inv, o1 = sv[1] * inv, o2 = sv[2] * inv, o3 = sv[3] * inv;
  float* outp = fout + (size_t)(g * 4) * HWdim + gy * Wdim + gx;
  outp[0] = o0;
  outp[(size_t)1 * HWdim] = o1;
  outp[(size_t)2 * HWdim] = o2;
  outp[(size_t)3 * HWdim] = o3;

  __syncthreads();                    // all read abuf traffic done
  *(f32x4*)(abuf + tid * 16) = (f32x4){o0, o1, o2, o3};
  __syncthreads();
  if (tid < 16) {                     // c = tid; g=c>>2, r=c&3
    const float* ap = (const float*)abuf;
    float sum = 0.f;
    for (int px = 0; px < 128; ++px) {
      int u = (px >> 4) * 64 + (tid >> 2) * 16 + (px & 15);
      sum += ap[u * 4 + (tid & 3)];
    }
    gadd(poolp + tid, sum * (1.0f / (float)HWdim));
  }
}

__global__ __launch_bounds__(512, 4) void k_fused(FusedArgs a) {
  __shared__ __align__(16) unsigned char smem[FX_SMEM];
  const int z = blockIdx.z;
  const int x0 = blockIdx.x * 16, y0 = blockIdx.y * 8;
  const int tid = threadIdx.x;
  if (z < 6) {
    const int si = z >> 1, b = z & 1;
    const unsigned* xp = a.xpad2 + (size_t)(b * 8) * XPL;
    float* pp = a.pooled + b * 16;
    if (si == 0)
      fused_body<7, true>(xp, a.simA[0], a.readA[0], a.fbgs[0] + (size_t)b * CHW, pp, smem, tid, x0, y0);
    else if (si == 1)
      fused_body<5, true>(xp, a.simA[1], a.readA[1], a.fbgs[1] + (size_t)b * CHW, pp, smem, tid, x0, y0);
    else
      fused_body<3, true>(xp, a.simA[2], a.readA[2], a.fbgs[2] + (size_t)b * CHW, pp, smem, tid, x0, y0);
  } else {
    const int zz = z - 6, si = zz >> 1, b = zz & 1;
    const unsigned* xp = a.xpad2 + (size_t)((2 + b) * 8) * XPL;
    float* pp = a.pooled + 32 + b * 16;
    if (si == 0)
      fused_body<7, false>(xp, a.simAtg[0], a.readAtg[0], a.ftgs[0] + (size_t)b * CHW, pp, smem, tid, x0, y0);
    else if (si == 1)
      fused_body<5, false>(xp, a.simAtg[1], a.readAtg[1], a.ftgs[1] + (size_t)b * CHW, pp, smem, tid, x0, y0);
    else
      fused_body<3, false>(xp, a.simAtg[2], a.readAtg[2], a.ftgs[2] + (size_t)b * CHW, pp, smem, tid, x0, y0);
  }
}

// ---------------------------------------------------------------------------
// Fusion MLP + softmax weights
// ---------------------------------------------------------------------------
__global__ __launch_bounds__(128) void k_mlp(
    const float* __restrict__ pooled,
    const float* __restrict__ w1b, const float* __restrict__ b1b,
    const float* __restrict__ w2b, const float* __restrict__ b2b,
    const float* __restrict__ w1t, const float* __restrict__ b1t,
    const float* __restrict__ w2t, const float* __restrict__ b2t,
    float* __restrict__ wt)
{
  __shared__ float hdn[Bdim][4];
  __shared__ float lg[Bdim][48];
  int t = threadIdx.x;
  for (int br = 0; br < 2; ++br) {
    const float* w1 = br ? w1t : w1b;
    const float* b1 = br ? b1t : b1b;
    const float* w2 = br ? w2t : w2b;
    const float* b2 = br ? b2t : b2b;
    if (t < 8) {
      int b = t >> 2, h = t & 3;
      float s = b1[h];
      for (int c = 0; c < C_CH; ++c) s += pooled[br * 32 + b * 16 + c] * w1[h * 16 + c];
      hdn[b][h] = fmaxf(s, 0.f);
    }
    __syncthreads();
    if (t < 96) {
      int b = t / 48, j = t - b * 48;
      float s = b2[j];
      for (int h = 0; h < 4; ++h) s += hdn[b][h] * w2[j * 4 + h];
      lg[b][j] = s;
    }
    __syncthreads();
    if (t < 32) {
      int b = t >> 4, c = t & 15;
      float l0 = lg[b][c], l1 = lg[b][16 + c], l2 = lg[b][32 + c];
      float m = fmaxf(l0, fmaxf(l1, l2));
      float e0 = __expf(l0 - m), e1 = __expf(l1 - m), e2 = __expf(l2 - m);
      float inv = 1.f / (e0 + e1 + e2);
      wt[((br * 2 + b) * 3 + 0) * 16 + c] = e0 * inv;
      wt[((br * 2 + b) * 3 + 1) * 16 + c] = e1 * inv;
      wt[((br * 2 + b) * 3 + 2) * 16 + c] = e2 * inv;
    }
    __syncthreads();
  }
}

__global__ __launch_bounds__(256) void k_out(const float* __restrict__ fbg,
                                             const float* __restrict__ ftg,
                                             const float* __restrict__ wt,
                                             float* __restrict__ out)
{
  int idx = blockIdx.x * 256 + threadIdx.x;      // 0 .. 2*PAIR_ELEMS-1
  int br  = idx >> 19;
  int rem = idx & ((1 << 19) - 1);
  int b   = rem >> 18;
  int off = rem & ((1 << 18) - 1);
  int c   = off >> 14;
  const float* f = (br == 0) ? fbg : ftg;
  int wbase = (br * 2 + b) * 3;
  float acc = 0.f;
#pragma unroll
  for (int s = 0; s < 3; ++s) {
    float v = f[(size_t)(s * 2 + b) * CHW + off];
    acc = fmaf(wt[(wbase + s) * 16 + c], v, acc);
  }
  out[idx] = acc;
}

// ---------------------------------------------------------------------------
extern "C" void kernel_launch(void* const* d_in, const int* in_sizes, int n_in,
                              void* d_out, int out_size, void* d_ws, size_t ws_size,
                              hipStream_t stream)
{
  const float* bg = (const float*)d_in[0];
  const float* tg = (const float*)d_in[1];
  const float* bg_mem[3]  = {(const float*)d_in[2],  (const float*)d_in[6],  (const float*)d_in[10]};
  const float* tg_mem[3]  = {(const float*)d_in[3],  (const float*)d_in[7],  (const float*)d_in[11]};
  const float* bg_temp[3] = {(const float*)d_in[4],  (const float*)d_in[8],  (const float*)d_in[12]};
  const float* tg_temp[3] = {(const float*)d_in[5],  (const float*)d_in[9],  (const float*)d_in[13]};
  const float* bg_fc1_w = (const float*)d_in[14];
  const float* bg_fc1_b = (const float*)d_in[15];
  const float* bg_fc2_w = (const float*)d_in[16];
  const float* bg_fc2_b = (const float*)d_in[17];
  const float* tg_fc1_w = (const float*)d_in[18];
  const float* tg_fc1_b = (const float*)d_in[19];
  const float* tg_fc2_w = (const float*)d_in[20];
  const float* tg_fc2_b = (const float*)d_in[21];

  unsigned* ws = (unsigned*)d_ws;
  unsigned* xpad2   = ws;                                    // 627,200 u32
  float*    pooled  = (float*)(ws + (size_t)32 * XPL);       // 64
  float*    wt      = pooled + 64;                           // 192
  _Float16* simA    = (_Float16*)(wt + 192);                 // 176,128 halfs
  _Float16* readA   = simA + 176128;                         // 176,128 halfs
  _Float16* simAtg  = readA + 176128;                        // 44,032 halfs
  _Float16* readAtg = simAtg + 44032;                        // 23,552 halfs
  float*    ftg     = (float*)(readAtg + 23552);             // 6*CHW
  float*    fbg     = ftg + (size_t)6 * CHW;                 // 6*CHW

  // zero xpad2 border + pooled/wt + all A arrays (pad slots) in one shot
  // = 627,200 + 256 + 88,064 + 88,064 + 22,016 + 11,776 = 837,376 u32
  hipMemsetAsync(xpad2, 0, (size_t)837376 * 4, stream);

  const int   Ms[6] = {64, 64, 64, 8, 8, 8};
  const int   Ps[6] = {3, 5, 7, 3, 5, 7};
  const float* mems[6]  = {bg_mem[0], bg_mem[1], bg_mem[2], tg_mem[0], tg_mem[1], tg_mem[2]};
  const float* temps[6] = {bg_temp[0], bg_temp[1], bg_temp[2], tg_temp[0], tg_temp[1], tg_temp[2]};

  // per-scale offsets (halfs), si 0..2 = P7,P5,P3
  const size_t aOff[3]   = {0, 102400, 155648};   // bg sim & read (same sizes)
  const size_t sOffTg[3] = {0, 25600, 38912};     // tg sim
  const size_t rOffTg[3] = {0, 13312, 20480};     // tg read

  PrepArgs pa;
  for (int k = 0; k < 6; ++k) {
    int D = C_CH * Ps[k] * Ps[k];
    int si = 2 - (k % 3);                         // PS index -> scale index
    if (k < 3)
      pa.d[k] = {mems[k], temps[k], simA + aOff[si], readA + aOff[si],
                 Ms[k], D, Ps[k], 0};
    else
      pa.d[k] = {mems[k], temps[k], simAtg + sOffTg[si], readAtg + rOffTg[si],
                 Ms[k], D, Ps[k], 1};
  }
  k_prep<<<dim3(196, 6), 256, 0, stream>>>(pa);
  k_padx<<<2048, 256, 0, stream>>>(bg, tg, xpad2);

  FusedArgs fa;
  fa.xpad2 = xpad2;
  fa.pooled = pooled;
  for (int si = 0; si < 3; ++si) {
    int p = 2 - si;
    fa.simA[si]    = simA + aOff[si];
    fa.readA[si]   = readA + aOff[si];
    fa.simAtg[si]  = simAtg + sOffTg[si];
    fa.readAtg[si] = readAtg + rOffTg[si];
    fa.fbgs[si]    = fbg + (size_t)p * 2 * CHW;
    fa.ftgs[si]    = ftg + (size_t)p * 2 * CHW;
  }

  k_fused<<<dim3(8, 16, 12), 512, 0, stream>>>(fa);

  k_mlp<<<1, 128, 0, stream>>>(pooled, bg_fc1_w, bg_fc1_b, bg_fc2_w, bg_fc2_b,
                               tg_fc1_w, tg_fc1_b, tg_fc2_w, tg_fc2_b, wt);
  k_out<<<(2 * PAIR_ELEMS) / 256, 256, 0, stream>>>(fbg, ftg, wt, (float*)d_out);
}